// Round 1
// baseline (819.104 us; speedup 1.0000x reference)
//
#include <hip/hip_runtime.h>
#include <hip/hip_bf16.h>
#include <math.h>

// Problem constants
#define B_    8
#define C_    768
#define N_    4096          // H*W = 64*64
#define RC_   16
#define CPG_  384           // channels per group (2 groups)
#define GCNT  ((size_t)CPG_ * N_)   // elements per (b,group) = 1572864
#define EPSV  1e-6f
#define LOG2E 1.4426950408889634f
#define SCALE 0.25f         // RC^-0.5

// ws layout (in floats):
//   [0,32)                      : group stats (16 groups x {sum, sumsq})
//   OFF_Q .. +B*N*RC            : qT[b][n][rc]   (later reused as aoT[b][n][rc])
//   OFF_K .. +B*N*RC            : kT[b][n][rc]
//   OFF_V .. +B*N*RC            : vT[b][n][rc]
//   OFF_PART ..                 : o_part[b][js][rc][n], m_part[b][js][n], l_part[b][js][n]
#define OFF_Q    32
#define OFF_K    (OFF_Q + B_*N_*RC_)
#define OFF_V    (OFF_K + B_*N_*RC_)
#define OFF_PART (OFF_V + B_*N_*RC_)

// ---------------------------------------------------------------- K0: zero stats
__global__ void k_zero(float* ws) {
    if (threadIdx.x < 32) ws[threadIdx.x] = 0.f;
}

// ---------------------------------------------------------------- K1: GN stats
// grid: 16 segments * 128 blocks, 256 threads. Each (b,g) segment is contiguous.
__global__ __launch_bounds__(256) void k_stats(const float* __restrict__ x,
                                               float* __restrict__ ws) {
    const int SB = 128;
    int seg = blockIdx.x / SB;      // b*2+g
    int blk = blockIdx.x % SB;
    const float4* xs = (const float4*)(x + (size_t)seg * GCNT);
    int idx = blk * 256 + threadIdx.x;              // 0..32767
    float s = 0.f, ss = 0.f;
#pragma unroll
    for (int it = 0; it < 12; ++it) {
        float4 v = xs[idx + it * (SB * 256)];
        s  += (v.x + v.y) + (v.z + v.w);
        ss += (v.x*v.x + v.y*v.y) + (v.z*v.z + v.w*v.w);
    }
    // wave reduce
    for (int off = 32; off; off >>= 1) {
        s  += __shfl_down(s, off);
        ss += __shfl_down(ss, off);
    }
    __shared__ float ps[4], pss[4];
    int wid = threadIdx.x >> 6, lane = threadIdx.x & 63;
    if (lane == 0) { ps[wid] = s; pss[wid] = ss; }
    __syncthreads();
    if (threadIdx.x == 0) {
        float a = (ps[0] + ps[1]) + (ps[2] + ps[3]);
        float b = (pss[0] + pss[1]) + (pss[2] + pss[3]);
        atomicAdd(&ws[seg * 2 + 0], a);
        atomicAdd(&ws[seg * 2 + 1], b);
    }
}

// ---------------------------------------------------------------- K2: GN apply + qkv 1x1 conv
// grid: B * 64 ntiles (ntile = 64 spatial). block 256 = 64 lanes x 4 mgroups.
// Each wave: one mgroup of 12 outputs (of 48 = q16|k16|v16) for 64 n's.
__global__ __launch_bounds__(256) void k_qkv(
        const float* __restrict__ x,
        const float* __restrict__ gn_w, const float* __restrict__ gn_b,
        const float* __restrict__ qw, const float* __restrict__ qb,
        const float* __restrict__ kw, const float* __restrict__ kb,
        const float* __restrict__ vw, const float* __restrict__ vb,
        float* __restrict__ ws) {
    int b = blockIdx.x >> 6;
    int ntile = blockIdx.x & 63;
    int nl = threadIdx.x & 63;
    int mg = threadIdx.x >> 6;      // 0..3, uniform per wave
    int n = ntile * 64 + nl;

    __shared__ float wlds[128 * 48];
    __shared__ float glds[128 * 2];

    float acc[12];
#pragma unroll
    for (int mi = 0; mi < 12; ++mi) {
        int m = mg * 12 + mi;
        acc[mi] = (m < 16) ? qb[m] : (m < 32) ? kb[m - 16] : vb[m - 32];
    }
    const float cntinv = 1.f / (float)GCNT;

    for (int ch = 0; ch < 6; ++ch) {
        int c0 = ch * 128;
        for (int idx = threadIdx.x; idx < 6144; idx += 256) {
            int cc = idx & 127, m = idx >> 7;
            int c = c0 + cc;
            float wv = (m < 16) ? qw[m * 768 + c]
                     : (m < 32) ? kw[(m - 16) * 768 + c]
                                : vw[(m - 32) * 768 + c];
            wlds[cc * 48 + m] = wv;
        }
        if (threadIdx.x < 256) {
            int cc = threadIdx.x & 127, w = threadIdx.x >> 7;
            glds[cc * 2 + w] = w ? gn_b[c0 + cc] : gn_w[c0 + cc];
        }
        __syncthreads();

        int g = (c0 >= 384) ? 1 : 0;
        float sum  = ws[(b * 2 + g) * 2 + 0];
        float ssum = ws[(b * 2 + g) * 2 + 1];
        float mean = sum * cntinv;
        float var  = ssum * cntinv - mean * mean;
        float rstd = rsqrtf(var + EPSV);

        const float4* w4 = (const float4*)wlds;
        for (int cc = 0; cc < 128; ++cc) {
            float xv = x[((size_t)(b * 768 + c0 + cc)) * N_ + n];
            float h = (xv - mean) * rstd * glds[cc * 2] + glds[cc * 2 + 1];
            float4 w0 = w4[cc * 12 + mg * 3 + 0];
            float4 w1 = w4[cc * 12 + mg * 3 + 1];
            float4 w2 = w4[cc * 12 + mg * 3 + 2];
            acc[0] = fmaf(h, w0.x, acc[0]);  acc[1]  = fmaf(h, w0.y, acc[1]);
            acc[2] = fmaf(h, w0.z, acc[2]);  acc[3]  = fmaf(h, w0.w, acc[3]);
            acc[4] = fmaf(h, w1.x, acc[4]);  acc[5]  = fmaf(h, w1.y, acc[5]);
            acc[6] = fmaf(h, w1.z, acc[6]);  acc[7]  = fmaf(h, w1.w, acc[7]);
            acc[8] = fmaf(h, w2.x, acc[8]);  acc[9]  = fmaf(h, w2.y, acc[9]);
            acc[10]= fmaf(h, w2.z, acc[10]); acc[11] = fmaf(h, w2.w, acc[11]);
        }
        __syncthreads();
    }

    float* qT = ws + OFF_Q;
    float* kT = ws + OFF_K;
    float* vT = ws + OFF_V;
    size_t nb = (size_t)(b * N_ + n) * RC_;
#pragma unroll
    for (int mi = 0; mi < 12; ++mi) {
        int m = mg * 12 + mi;
        if (m < 16)      qT[nb + m]        = acc[mi];
        else if (m < 32) kT[nb + (m - 16)] = acc[mi];
        else             vT[nb + (m - 32)] = acc[mi];
    }
}

// ---------------------------------------------------------------- K3: flash attention (fp32)
// grid: ((b*4 + itile)*JS + js). block 256 threads, each owns 4 rows (i), scans jrange keys.
__global__ __launch_bounds__(256, 1) void k_attn(
        const float* __restrict__ qT, const float* __restrict__ kT,
        const float* __restrict__ vT,
        float* __restrict__ opart, float* __restrict__ mpart, float* __restrict__ lpart,
        int JS, int jrange) {
    int js = blockIdx.x % JS;
    int t  = blockIdx.x / JS;
    int itile = t & 3;
    int b = t >> 2;
    int tid = threadIdx.x;

    float q[4][16], o[4][16], m[4], l[4];
#pragma unroll
    for (int it = 0; it < 4; ++it) {
        int i = itile * 1024 + it * 256 + tid;
        const float* qp = &qT[(size_t)(b * N_ + i) * RC_];
#pragma unroll
        for (int r = 0; r < 16; ++r) q[it][r] = qp[r] * (SCALE * LOG2E);
        m[it] = -1e30f; l[it] = 0.f;
#pragma unroll
        for (int r = 0; r < 16; ++r) o[it][r] = 0.f;
    }

    int j0 = js * jrange;
#pragma unroll 2
    for (int j = j0; j < j0 + jrange; ++j) {
        const float* kp = &kT[(size_t)(b * N_ + j) * RC_];
        const float* vp = &vT[(size_t)(b * N_ + j) * RC_];
        float kv[16], vv[16];
#pragma unroll
        for (int r = 0; r < 16; ++r) { kv[r] = kp[r]; vv[r] = vp[r]; }
#pragma unroll
        for (int it = 0; it < 4; ++it) {
            float s0 = 0.f, s1 = 0.f, s2 = 0.f, s3 = 0.f;
#pragma unroll
            for (int r = 0; r < 16; r += 4) {
                s0 = fmaf(q[it][r + 0], kv[r + 0], s0);
                s1 = fmaf(q[it][r + 1], kv[r + 1], s1);
                s2 = fmaf(q[it][r + 2], kv[r + 2], s2);
                s3 = fmaf(q[it][r + 3], kv[r + 3], s3);
            }
            float s = (s0 + s1) + (s2 + s3);      // already in log2 domain
            if (s > m[it]) {
                float al = exp2f(m[it] - s);
                m[it] = s;
                l[it] *= al;
#pragma unroll
                for (int r = 0; r < 16; ++r) o[it][r] *= al;
            }
            float p = exp2f(s - m[it]);
            l[it] += p;
#pragma unroll
            for (int r = 0; r < 16; ++r) o[it][r] = fmaf(p, vv[r], o[it][r]);
        }
    }

#pragma unroll
    for (int it = 0; it < 4; ++it) {
        int i = itile * 1024 + it * 256 + tid;
        size_t base = ((size_t)(b * JS + js) * RC_) * N_ + i;
#pragma unroll
        for (int r = 0; r < 16; ++r) opart[base + (size_t)r * N_] = o[it][r];
        mpart[(size_t)(b * JS + js) * N_ + i] = m[it];
        lpart[(size_t)(b * JS + js) * N_ + i] = l[it];
    }
}

// ---------------------------------------------------------------- K3b: merge j-split partials
// grid: 128 blocks x 256. One thread per (b,i). Writes aoT[b][i][rc] (reuses q region).
__global__ __launch_bounds__(256) void k_amerge(
        const float* __restrict__ opart, const float* __restrict__ mpart,
        const float* __restrict__ lpart, float* __restrict__ aoT, int JS) {
    int gid = blockIdx.x * 256 + threadIdx.x;
    int b = gid >> 12, i = gid & 4095;

    float M = -1e30f;
    for (int js = 0; js < JS; ++js)
        M = fmaxf(M, mpart[(size_t)(b * JS + js) * N_ + i]);
    float w[8];
    float L = 0.f;
    for (int js = 0; js < JS; ++js) {
        float mv = mpart[(size_t)(b * JS + js) * N_ + i];
        float lv = lpart[(size_t)(b * JS + js) * N_ + i];
        w[js] = exp2f(mv - M);
        L = fmaf(lv, w[js], L);
    }
    float inv = 1.f / L;
    float out[16];
#pragma unroll
    for (int r = 0; r < 16; ++r) out[r] = 0.f;
    for (int js = 0; js < JS; ++js) {
        size_t base = ((size_t)(b * JS + js) * RC_) * N_ + i;
#pragma unroll
        for (int r = 0; r < 16; ++r)
            out[r] = fmaf(opart[base + (size_t)r * N_], w[js], out[r]);
    }
    size_t ob = (size_t)(b * N_ + i) * RC_;
#pragma unroll
    for (int r = 0; r < 16; ++r) aoT[ob + r] = out[r] * inv;
}

// ---------------------------------------------------------------- K4: proj (RC->C) + residual
// grid: (b*16 + ntile)*6 + cchunk. block 256, one thread per n, 128 channels per block.
__global__ __launch_bounds__(256) void k_proj(
        const float* __restrict__ x, const float* __restrict__ pw,
        const float* __restrict__ pb, const float* __restrict__ aoT,
        float* __restrict__ out) {
    int ch = blockIdx.x % 6;
    int t  = blockIdx.x / 6;
    int ntile = t & 15;
    int b = t >> 4;
    int n = ntile * 256 + threadIdx.x;

    const float4* a4 = (const float4*)&aoT[(size_t)(b * N_ + n) * RC_];
    float4 A0 = a4[0], A1 = a4[1], A2 = a4[2], A3 = a4[3];
    float av[16] = {A0.x, A0.y, A0.z, A0.w, A1.x, A1.y, A1.z, A1.w,
                    A2.x, A2.y, A2.z, A2.w, A3.x, A3.y, A3.z, A3.w};

    __shared__ float plds[128 * 16];
    __shared__ float pblds[128];
    int c0 = ch * 128;
    for (int idx = threadIdx.x; idx < 2048; idx += 256)
        plds[idx] = pw[(size_t)c0 * 16 + idx];
    if (threadIdx.x < 128) pblds[threadIdx.x] = pb[c0 + threadIdx.x];
    __syncthreads();

    for (int cc = 0; cc < 128; ++cc) {
        size_t xi = ((size_t)(b * 768 + c0 + cc)) * N_ + n;
        float acc = pblds[cc] + x[xi];
#pragma unroll
        for (int r = 0; r < 16; ++r)
            acc = fmaf(av[r], plds[cc * 16 + r], acc);
        out[xi] = acc;
    }
}

// ---------------------------------------------------------------- launch
extern "C" void kernel_launch(void* const* d_in, const int* in_sizes, int n_in,
                              void* d_out, int out_size, void* d_ws, size_t ws_size,
                              hipStream_t stream) {
    const float* x    = (const float*)d_in[0];
    const float* gn_w = (const float*)d_in[1];
    const float* gn_b = (const float*)d_in[2];
    const float* qw   = (const float*)d_in[3];
    const float* qb   = (const float*)d_in[4];
    const float* kw   = (const float*)d_in[5];
    const float* kb   = (const float*)d_in[6];
    const float* vw   = (const float*)d_in[7];
    const float* vb   = (const float*)d_in[8];
    const float* pw   = (const float*)d_in[9];
    const float* pb   = (const float*)d_in[10];
    float* out = (float*)d_out;
    float* wsf = (float*)d_ws;

    // pick JS (j-split) to fit workspace
    size_t avail = ws_size / 4;   // floats
    int JS = 8;
    while (JS > 1) {
        size_t need = (size_t)OFF_PART + (size_t)JS * ((size_t)B_ * RC_ * N_ + 2 * (size_t)B_ * N_);
        if (need <= avail) break;
        JS >>= 1;
    }
    int jrange = N_ / JS;

    float* qT = wsf + OFF_Q;
    float* kT = wsf + OFF_K;
    float* vT = wsf + OFF_V;
    float* opart = wsf + OFF_PART;
    float* mpart = opart + (size_t)B_ * JS * RC_ * N_;
    float* lpart = mpart + (size_t)B_ * JS * N_;

    k_zero<<<1, 64, 0, stream>>>(wsf);
    k_stats<<<16 * 128, 256, 0, stream>>>(x, wsf);
    k_qkv<<<B_ * 64, 256, 0, stream>>>(x, gn_w, gn_b, qw, qb, kw, kb, vw, vb, wsf);
    k_attn<<<B_ * 4 * JS, 256, 0, stream>>>(qT, kT, vT, opart, mpart, lpart, JS, jrange);
    k_amerge<<<128, 256, 0, stream>>>(opart, mpart, lpart, qT /* reused as aoT */, JS);
    k_proj<<<B_ * 16 * 6, 256, 0, stream>>>(x, pw, pb, qT, out);
}

// Round 3
// 501.658 us; speedup vs baseline: 1.6328x; 1.6328x over previous
//
#include <hip/hip_runtime.h>
#include <hip/hip_bf16.h>
#include <math.h>

// Problem constants
#define B_    8
#define C_    768
#define N_    4096          // H*W = 64*64
#define RC_   16
#define CPG_  384           // channels per group (2 groups)
#define GCNT  ((size_t)CPG_ * N_)   // elements per (b,group) = 1572864
#define EPSV  1e-6f
#define LOG2E 1.4426950408889634f
#define SCALE 0.25f         // RC^-0.5

// ws layout (in floats):
//   [0,32)                      : group stats (16 groups x {sum, sumsq})
//   OFF_Q .. +B*N*RC            : qT[b][n][rc]   (later reused as aoT[b][n][rc])
//   OFF_K .. +B*N*RC            : kT[b][n][rc]
//   OFF_V .. +B*N*RC            : vT[b][n][rc]
//   OFF_PART ..                 : o_part[b][js][rc][n], m_part[b][js][n], l_part[b][js][n]
#define OFF_Q    32
#define OFF_K    (OFF_Q + B_*N_*RC_)
#define OFF_V    (OFF_K + B_*N_*RC_)
#define OFF_PART (OFF_V + B_*N_*RC_)

// ---------------------------------------------------------------- K0: zero stats
__global__ void k_zero(float* ws) {
    if (threadIdx.x < 32) ws[threadIdx.x] = 0.f;
}

// ---------------------------------------------------------------- K1: GN stats
// grid: 16 segments * 128 blocks, 256 threads. Each (b,g) segment is contiguous.
__global__ __launch_bounds__(256) void k_stats(const float* __restrict__ x,
                                               float* __restrict__ ws) {
    const int SB = 128;
    int seg = blockIdx.x / SB;      // b*2+g
    int blk = blockIdx.x % SB;
    const float4* xs = (const float4*)(x + (size_t)seg * GCNT);
    int idx = blk * 256 + threadIdx.x;              // 0..32767
    float s = 0.f, ss = 0.f;
#pragma unroll
    for (int it = 0; it < 12; ++it) {
        float4 v = xs[idx + it * (SB * 256)];
        s  += (v.x + v.y) + (v.z + v.w);
        ss += (v.x*v.x + v.y*v.y) + (v.z*v.z + v.w*v.w);
    }
    for (int off = 32; off; off >>= 1) {
        s  += __shfl_down(s, off);
        ss += __shfl_down(ss, off);
    }
    __shared__ float ps[4], pss[4];
    int wid = threadIdx.x >> 6, lane = threadIdx.x & 63;
    if (lane == 0) { ps[wid] = s; pss[wid] = ss; }
    __syncthreads();
    if (threadIdx.x == 0) {
        float a = (ps[0] + ps[1]) + (ps[2] + ps[3]);
        float b = (pss[0] + pss[1]) + (pss[2] + pss[3]);
        atomicAdd(&ws[seg * 2 + 0], a);
        atomicAdd(&ws[seg * 2 + 1], b);
    }
}

// ---------------------------------------------------------------- K2: GN apply + qkv 1x1 conv
// grid: B * 64 ntiles (ntile = 64 spatial). block 256 = 64 lanes x 4 mgroups.
// x-tile (128 c x 64 n) is staged ONCE per chunk into LDS with GN pre-applied,
// removing the 4x redundant global reads across the 4 waves.
__global__ __launch_bounds__(256) void k_qkv(
        const float* __restrict__ x,
        const float* __restrict__ gn_w, const float* __restrict__ gn_b,
        const float* __restrict__ qw, const float* __restrict__ qb,
        const float* __restrict__ kw, const float* __restrict__ kb,
        const float* __restrict__ vw, const float* __restrict__ vb,
        float* __restrict__ ws) {
    int b = blockIdx.x >> 6;
    int ntile = blockIdx.x & 63;
    int nl = threadIdx.x & 63;
    int mg = threadIdx.x >> 6;      // 0..3, uniform per wave
    int n = ntile * 64 + nl;

    __shared__ float wlds[128 * 48];   // weights, m-minor
    __shared__ float xlds[128 * 64];   // normalized x chunk

    float acc[12];
#pragma unroll
    for (int mi = 0; mi < 12; ++mi) {
        int m = mg * 12 + mi;
        acc[mi] = (m < 16) ? qb[m] : (m < 32) ? kb[m - 16] : vb[m - 32];
    }
    const float cntinv = 1.f / (float)GCNT;

    for (int ch = 0; ch < 6; ++ch) {
        int c0 = ch * 128;
        int g = (c0 >= 384) ? 1 : 0;
        float sum  = ws[(b * 2 + g) * 2 + 0];
        float ssum = ws[(b * 2 + g) * 2 + 1];
        float mean = sum * cntinv;
        float var  = ssum * cntinv - mean * mean;
        float rstd = rsqrtf(var + EPSV);

        // stage weights
        for (int idx = threadIdx.x; idx < 6144; idx += 256) {
            int cc = idx & 127, m = idx >> 7;
            int c = c0 + cc;
            float wv = (m < 16) ? qw[m * 768 + c]
                     : (m < 32) ? kw[(m - 16) * 768 + c]
                                : vw[(m - 32) * 768 + c];
            wlds[cc * 48 + m] = wv;
        }
        // stage normalized x tile: xlds[cc][n] = (x - mean)*rstd*gamma + beta
        for (int idx = threadIdx.x; idx < 2048; idx += 256) {
            int cc = idx >> 4, n4 = idx & 15;
            const float4* xp = (const float4*)(x + ((size_t)(b * 768 + c0 + cc)) * N_ + ntile * 64);
            float4 v = xp[n4];
            float a = rstd * gn_w[c0 + cc];
            float c = gn_b[c0 + cc] - mean * a;
            float4 h = {fmaf(v.x, a, c), fmaf(v.y, a, c), fmaf(v.z, a, c), fmaf(v.w, a, c)};
            *(float4*)&xlds[cc * 64 + n4 * 4] = h;
        }
        __syncthreads();

        const float4* w4 = (const float4*)wlds;
#pragma unroll 4
        for (int cc = 0; cc < 128; ++cc) {
            float h = xlds[cc * 64 + nl];
            float4 w0 = w4[cc * 12 + mg * 3 + 0];
            float4 w1 = w4[cc * 12 + mg * 3 + 1];
            float4 w2 = w4[cc * 12 + mg * 3 + 2];
            acc[0] = fmaf(h, w0.x, acc[0]);  acc[1]  = fmaf(h, w0.y, acc[1]);
            acc[2] = fmaf(h, w0.z, acc[2]);  acc[3]  = fmaf(h, w0.w, acc[3]);
            acc[4] = fmaf(h, w1.x, acc[4]);  acc[5]  = fmaf(h, w1.y, acc[5]);
            acc[6] = fmaf(h, w1.z, acc[6]);  acc[7]  = fmaf(h, w1.w, acc[7]);
            acc[8] = fmaf(h, w2.x, acc[8]);  acc[9]  = fmaf(h, w2.y, acc[9]);
            acc[10]= fmaf(h, w2.z, acc[10]); acc[11] = fmaf(h, w2.w, acc[11]);
        }
        __syncthreads();
    }

    float* qT = ws + OFF_Q;
    float* kT = ws + OFF_K;
    float* vT = ws + OFF_V;
    size_t nb = (size_t)(b * N_ + n) * RC_;
#pragma unroll
    for (int mi = 0; mi < 12; ++mi) {
        int m = mg * 12 + mi;
        if (m < 16)      qT[nb + m]        = acc[mi];
        else if (m < 32) kT[nb + (m - 16)] = acc[mi];
        else             vT[nb + (m - 32)] = acc[mi];
    }
}

// ---------------------------------------------------------------- K3: flash attention (fp32)
// grid: ((b*16 + itile)*JS + js). block 256 threads, ONE row per thread.
__global__ __launch_bounds__(256) void k_attn(
        const float* __restrict__ qT, const float* __restrict__ kT,
        const float* __restrict__ vT,
        float* __restrict__ opart, float* __restrict__ mpart, float* __restrict__ lpart,
        int JS, int jrange) {
    int js = blockIdx.x % JS;
    int t  = blockIdx.x / JS;
    int itile = t & 15;
    int b = t >> 4;
    int tid = threadIdx.x;
    int i = itile * 256 + tid;

    float q[16], o[16], m, l;
    {
        const float* qp = &qT[(size_t)(b * N_ + i) * RC_];
#pragma unroll
        for (int r = 0; r < 16; ++r) q[r] = qp[r] * (SCALE * LOG2E);
    }
    m = -1e30f; l = 0.f;
#pragma unroll
    for (int r = 0; r < 16; ++r) o[r] = 0.f;

    int j0 = js * jrange;
#pragma unroll 2
    for (int j = j0; j < j0 + jrange; ++j) {
        const float* kp = &kT[(size_t)(b * N_ + j) * RC_];
        const float* vp = &vT[(size_t)(b * N_ + j) * RC_];
        float kv[16], vv[16];
#pragma unroll
        for (int r = 0; r < 16; ++r) { kv[r] = kp[r]; vv[r] = vp[r]; }
        float s0 = 0.f, s1 = 0.f, s2 = 0.f, s3 = 0.f;
#pragma unroll
        for (int r = 0; r < 16; r += 4) {
            s0 = fmaf(q[r + 0], kv[r + 0], s0);
            s1 = fmaf(q[r + 1], kv[r + 1], s1);
            s2 = fmaf(q[r + 2], kv[r + 2], s2);
            s3 = fmaf(q[r + 3], kv[r + 3], s3);
        }
        float s = (s0 + s1) + (s2 + s3);      // log2-domain
        if (s > m) {
            float al = exp2f(m - s);
            m = s;
            l *= al;
#pragma unroll
            for (int r = 0; r < 16; ++r) o[r] *= al;
        }
        float p = exp2f(s - m);
        l += p;
#pragma unroll
        for (int r = 0; r < 16; ++r) o[r] = fmaf(p, vv[r], o[r]);
    }

    size_t base = ((size_t)(b * JS + js) * RC_) * N_ + i;
#pragma unroll
    for (int r = 0; r < 16; ++r) opart[base + (size_t)r * N_] = o[r];
    mpart[(size_t)(b * JS + js) * N_ + i] = m;
    lpart[(size_t)(b * JS + js) * N_ + i] = l;
}

// ---------------------------------------------------------------- K3b: merge j-split partials
// grid: 512 blocks x 256. One thread per (b, i, r-group-of-4). Coalesced over i.
__global__ __launch_bounds__(256) void k_amerge(
        const float* __restrict__ opart, const float* __restrict__ mpart,
        const float* __restrict__ lpart, float* __restrict__ aoT, int JS) {
    int gid = blockIdx.x * 256 + threadIdx.x;   // 131072 total
    int i  = gid & 4095;
    int t2 = gid >> 12;          // 0..31
    int b  = t2 >> 2;
    int rg = t2 & 3;             // r-group: rows rg*4 .. rg*4+3

    float M = -1e30f;
    for (int js = 0; js < JS; ++js)
        M = fmaxf(M, mpart[(size_t)(b * JS + js) * N_ + i]);
    float w[16];
    float L = 0.f;
    for (int js = 0; js < JS; ++js) {
        float mv = mpart[(size_t)(b * JS + js) * N_ + i];
        float lv = lpart[(size_t)(b * JS + js) * N_ + i];
        w[js] = exp2f(mv - M);
        L = fmaf(lv, w[js], L);
    }
    float inv = 1.f / L;
    float out[4] = {0.f, 0.f, 0.f, 0.f};
    for (int js = 0; js < JS; ++js) {
        size_t base = ((size_t)(b * JS + js) * RC_ + rg * 4) * N_ + i;
#pragma unroll
        for (int r = 0; r < 4; ++r)
            out[r] = fmaf(opart[base + (size_t)r * N_], w[js], out[r]);
    }
    float4 res = {out[0] * inv, out[1] * inv, out[2] * inv, out[3] * inv};
    *(float4*)&aoT[((size_t)(b * N_ + i) * RC_) + rg * 4] = res;
}

// ---------------------------------------------------------------- K4: proj (RC->C) + residual
__global__ __launch_bounds__(256) void k_proj(
        const float* __restrict__ x, const float* __restrict__ pw,
        const float* __restrict__ pb, const float* __restrict__ aoT,
        float* __restrict__ out) {
    int ch = blockIdx.x % 6;
    int t  = blockIdx.x / 6;
    int ntile = t & 15;
    int b = t >> 4;
    int n = ntile * 256 + threadIdx.x;

    const float4* a4 = (const float4*)&aoT[(size_t)(b * N_ + n) * RC_];
    float4 A0 = a4[0], A1 = a4[1], A2 = a4[2], A3 = a4[3];
    float av[16] = {A0.x, A0.y, A0.z, A0.w, A1.x, A1.y, A1.z, A1.w,
                    A2.x, A2.y, A2.z, A2.w, A3.x, A3.y, A3.z, A3.w};

    __shared__ float plds[128 * 16];
    __shared__ float pblds[128];
    int c0 = ch * 128;
    for (int idx = threadIdx.x; idx < 2048; idx += 256)
        plds[idx] = pw[(size_t)c0 * 16 + idx];
    if (threadIdx.x < 128) pblds[threadIdx.x] = pb[c0 + threadIdx.x];
    __syncthreads();

    for (int cc = 0; cc < 128; ++cc) {
        size_t xi = ((size_t)(b * 768 + c0 + cc)) * N_ + n;
        const float* wp = &plds[cc * 16];
        // 4 independent partial chains (break the 16-deep dependency)
        float t0 = fmaf(av[0],  wp[0],  pblds[cc] + x[xi]);
        float t1 = fmaf(av[1],  wp[1],  0.f);
        float t2 = fmaf(av[2],  wp[2],  0.f);
        float t3 = fmaf(av[3],  wp[3],  0.f);
#pragma unroll
        for (int r = 4; r < 16; r += 4) {
            t0 = fmaf(av[r + 0], wp[r + 0], t0);
            t1 = fmaf(av[r + 1], wp[r + 1], t1);
            t2 = fmaf(av[r + 2], wp[r + 2], t2);
            t3 = fmaf(av[r + 3], wp[r + 3], t3);
        }
        out[xi] = (t0 + t1) + (t2 + t3);
    }
}

// ---------------------------------------------------------------- launch
extern "C" void kernel_launch(void* const* d_in, const int* in_sizes, int n_in,
                              void* d_out, int out_size, void* d_ws, size_t ws_size,
                              hipStream_t stream) {
    const float* x    = (const float*)d_in[0];
    const float* gn_w = (const float*)d_in[1];
    const float* gn_b = (const float*)d_in[2];
    const float* qw   = (const float*)d_in[3];
    const float* qb   = (const float*)d_in[4];
    const float* kw   = (const float*)d_in[5];
    const float* kb   = (const float*)d_in[6];
    const float* vw   = (const float*)d_in[7];
    const float* vb   = (const float*)d_in[8];
    const float* pw   = (const float*)d_in[9];
    const float* pb   = (const float*)d_in[10];
    float* out = (float*)d_out;
    float* wsf = (float*)d_ws;

    // pick JS (j-split) to fit workspace; prefer 16 for occupancy
    size_t avail = ws_size / 4;   // floats
    int JS = 16;
    while (JS > 1) {
        size_t need = (size_t)OFF_PART + (size_t)JS * ((size_t)B_ * RC_ * N_ + 2 * (size_t)B_ * N_);
        if (need <= avail) break;
        JS >>= 1;
    }
    int jrange = N_ / JS;

    float* qT = wsf + OFF_Q;
    float* kT = wsf + OFF_K;
    float* vT = wsf + OFF_V;
    float* opart = wsf + OFF_PART;
    float* mpart = opart + (size_t)B_ * JS * RC_ * N_;
    float* lpart = mpart + (size_t)B_ * JS * N_;

    k_zero<<<1, 64, 0, stream>>>(wsf);
    k_stats<<<16 * 128, 256, 0, stream>>>(x, wsf);
    k_qkv<<<B_ * 64, 256, 0, stream>>>(x, gn_w, gn_b, qw, qb, kw, kb, vw, vb, wsf);
    k_attn<<<B_ * 16 * JS, 256, 0, stream>>>(qT, kT, vT, opart, mpart, lpart, JS, jrange);
    k_amerge<<<512, 256, 0, stream>>>(opart, mpart, lpart, qT /* reused as aoT */, JS);
    k_proj<<<B_ * 16 * 6, 256, 0, stream>>>(x, pw, pb, qT, out);
}

// Round 6
// 382.099 us; speedup vs baseline: 2.1437x; 1.3129x over previous
//
#include <hip/hip_runtime.h>
#include <hip/hip_bf16.h>
#include <math.h>

// Problem constants
#define B_    8
#define C_    768
#define N_    4096          // H*W = 64*64
#define RC_   16
#define CPG_  384           // channels per group (2 groups)
#define GCNT  ((size_t)CPG_ * N_)   // elements per (b,group) = 1572864
#define EPSV  1e-6f
#define LOG2E 1.4426950408889634f
#define SCALE 0.25f         // RC^-0.5
#define QPRE  (SCALE * LOG2E)

// ws layout (floats):
//   [0,32)     : group stats
//   OFF_AO     : aoT f32 [B][N][16]  (amerge out, proj in)
//   OFF_QB/KB  : qB,kB bf16 [B][N][16]  (as ushort; q pre-scaled by QPRE)
//   OFF_VB     : vBt bf16 [B][16][N]
//   OFF_PART   : opart[b][js][rc][n] f32, mpart[b][js][n], lpart[b][js][n]
#define OFF_AO   32
#define AO_SZ    (B_*N_*RC_)
#define OFF_QB   (OFF_AO + AO_SZ)
#define QB_SZF   (B_*N_*RC_/2)
#define OFF_KB   (OFF_QB + QB_SZF)
#define OFF_VB   (OFF_KB + QB_SZF)
#define OFF_PART (OFF_VB + QB_SZF)

typedef __attribute__((ext_vector_type(8)))  short bf16x8;
typedef __attribute__((ext_vector_type(16))) float f32x16;
typedef unsigned int  u32;
typedef unsigned short ushort_t;

__device__ inline ushort_t f2bf(float f) {
    __hip_bfloat16 h = __float2bfloat16(f);
    return *reinterpret_cast<ushort_t*>(&h);
}

// ---------------------------------------------------------------- K0: zero stats
__global__ void k_zero(float* ws) {
    if (threadIdx.x < 32) ws[threadIdx.x] = 0.f;
}

// ---------------------------------------------------------------- K1: GN stats
__global__ __launch_bounds__(256) void k_stats(const float* __restrict__ x,
                                               float* __restrict__ ws) {
    const int SB = 128;
    int seg = blockIdx.x / SB;      // b*2+g
    int blk = blockIdx.x % SB;
    const float4* xs = (const float4*)(x + (size_t)seg * GCNT);
    int idx = blk * 256 + threadIdx.x;
    float s = 0.f, ss = 0.f;
#pragma unroll
    for (int it = 0; it < 12; ++it) {
        float4 v = xs[idx + it * (SB * 256)];
        s  += (v.x + v.y) + (v.z + v.w);
        ss += (v.x*v.x + v.y*v.y) + (v.z*v.z + v.w*v.w);
    }
    for (int off = 32; off; off >>= 1) {
        s  += __shfl_down(s, off);
        ss += __shfl_down(ss, off);
    }
    __shared__ float ps[4], pss[4];
    int wid = threadIdx.x >> 6, lane = threadIdx.x & 63;
    if (lane == 0) { ps[wid] = s; pss[wid] = ss; }
    __syncthreads();
    if (threadIdx.x == 0) {
        float a = (ps[0] + ps[1]) + (ps[2] + ps[3]);
        float b = (pss[0] + pss[1]) + (pss[2] + pss[3]);
        atomicAdd(&ws[seg * 2 + 0], a);
        atomicAdd(&ws[seg * 2 + 1], b);
    }
}

// ---------------------------------------------------------------- K2: GN apply + qkv 1x1 conv
// Outputs bf16: qB (pre-scaled), kB ([b][n][16]) and vBt ([b][16][n]).
__global__ __launch_bounds__(256) void k_qkv(
        const float* __restrict__ x,
        const float* __restrict__ gn_w, const float* __restrict__ gn_b,
        const float* __restrict__ qw, const float* __restrict__ qb,
        const float* __restrict__ kw, const float* __restrict__ kb,
        const float* __restrict__ vw, const float* __restrict__ vb,
        float* __restrict__ ws) {
    int b = blockIdx.x >> 6;
    int ntile = blockIdx.x & 63;
    int nl = threadIdx.x & 63;
    int mg = threadIdx.x >> 6;      // 0..3, uniform per wave
    int n = ntile * 64 + nl;

    __shared__ float wlds[128 * 48];   // weights, m-minor
    __shared__ float xlds[128 * 64];   // normalized x chunk

    float acc[12];
#pragma unroll
    for (int mi = 0; mi < 12; ++mi) {
        int m = mg * 12 + mi;
        acc[mi] = (m < 16) ? qb[m] : (m < 32) ? kb[m - 16] : vb[m - 32];
    }
    const float cntinv = 1.f / (float)GCNT;

    for (int ch = 0; ch < 6; ++ch) {
        int c0 = ch * 128;
        int g = (c0 >= 384) ? 1 : 0;
        float sum  = ws[(b * 2 + g) * 2 + 0];
        float ssum = ws[(b * 2 + g) * 2 + 1];
        float mean = sum * cntinv;
        float var  = ssum * cntinv - mean * mean;
        float rstd = rsqrtf(var + EPSV);

        for (int idx = threadIdx.x; idx < 6144; idx += 256) {
            int cc = idx & 127, m = idx >> 7;
            int c = c0 + cc;
            float wv = (m < 16) ? qw[m * 768 + c]
                     : (m < 32) ? kw[(m - 16) * 768 + c]
                                : vw[(m - 32) * 768 + c];
            wlds[cc * 48 + m] = wv;
        }
        for (int idx = threadIdx.x; idx < 2048; idx += 256) {
            int cc = idx >> 4, n4 = idx & 15;
            const float4* xp = (const float4*)(x + ((size_t)(b * 768 + c0 + cc)) * N_ + ntile * 64);
            float4 v = xp[n4];
            float a = rstd * gn_w[c0 + cc];
            float c = gn_b[c0 + cc] - mean * a;
            float4 h = {fmaf(v.x, a, c), fmaf(v.y, a, c), fmaf(v.z, a, c), fmaf(v.w, a, c)};
            *(float4*)&xlds[cc * 64 + n4 * 4] = h;
        }
        __syncthreads();

        const float4* w4 = (const float4*)wlds;
#pragma unroll 4
        for (int cc = 0; cc < 128; ++cc) {
            float h = xlds[cc * 64 + nl];
            float4 w0 = w4[cc * 12 + mg * 3 + 0];
            float4 w1 = w4[cc * 12 + mg * 3 + 1];
            float4 w2 = w4[cc * 12 + mg * 3 + 2];
            acc[0] = fmaf(h, w0.x, acc[0]);  acc[1]  = fmaf(h, w0.y, acc[1]);
            acc[2] = fmaf(h, w0.z, acc[2]);  acc[3]  = fmaf(h, w0.w, acc[3]);
            acc[4] = fmaf(h, w1.x, acc[4]);  acc[5]  = fmaf(h, w1.y, acc[5]);
            acc[6] = fmaf(h, w1.z, acc[6]);  acc[7]  = fmaf(h, w1.w, acc[7]);
            acc[8] = fmaf(h, w2.x, acc[8]);  acc[9]  = fmaf(h, w2.y, acc[9]);
            acc[10]= fmaf(h, w2.z, acc[10]); acc[11] = fmaf(h, w2.w, acc[11]);
        }
        __syncthreads();
    }

    ushort_t* qB  = (ushort_t*)(ws + OFF_QB);
    ushort_t* kB  = (ushort_t*)(ws + OFF_KB);
    ushort_t* vBt = (ushort_t*)(ws + OFF_VB);
    size_t nb = (size_t)(b * N_ + n) * RC_;
#pragma unroll
    for (int mi = 0; mi < 12; ++mi) {
        int m = mg * 12 + mi;
        if (m < 16)      qB[nb + m]        = f2bf(acc[mi] * QPRE);
        else if (m < 32) kB[nb + (m - 16)] = f2bf(acc[mi]);
        else             vBt[((size_t)b * RC_ + (m - 32)) * N_ + n] = f2bf(acc[mi]);
    }
}

// ---------------------------------------------------------------- K3: MFMA flash attention
// grid: ((b*32 + itile)*JS + js), 256 threads = 4 waves, each wave owns 32 i-rows.
// QK^T swapped: D=mfma(K,Q) -> lane holds i=lane&31, 16 j's in regs.
__global__ __launch_bounds__(256) void k_attn(
        const ushort_t* __restrict__ qB, const ushort_t* __restrict__ kB,
        const ushort_t* __restrict__ vBt,
        float* __restrict__ opart, float* __restrict__ mpart, float* __restrict__ lpart,
        int JS, int jrange) {
    int js = blockIdx.x % JS;
    int t  = blockIdx.x / JS;
    int itile = t & 31;
    int b = t >> 5;
    int wave = threadIdx.x >> 6;
    int lane = threadIdx.x & 63;
    int hi   = lane >> 5;
    int l31  = lane & 31;
    int i0 = itile * 128 + wave * 32;
    int rcv = (l31 < 16) ? l31 : 15;   // clamp for PV B-operand (cols 16-31 unused)

    // Q fragment (B-operand): qB[(b*N + i0 + l31)*16 + hi*8 ..]
    bf16x8 qf = *(const bf16x8*)&qB[((size_t)b * N_ + i0 + l31) * RC_ + hi * 8];

    f32x16 o;
#pragma unroll
    for (int r = 0; r < 16; ++r) o[r] = 0.f;
    float m = -1e30f, l = 0.f;

    int j0 = js * jrange;
    const ushort_t* kbase = kB + (size_t)b * N_ * RC_;
    const ushort_t* vbase = vBt + ((size_t)b * RC_ + rcv) * N_;

    // prologue loads
    bf16x8 kf  = *(const bf16x8*)&kbase[(size_t)(j0 + l31) * RC_ + hi * 8];
    bf16x8 vf0 = *(const bf16x8*)&vbase[j0 + hi * 8];
    bf16x8 vf1 = *(const bf16x8*)&vbase[j0 + 16 + hi * 8];

    for (int jt = 0; jt < jrange; jt += 32) {
        int jn = j0 + jt + 32;
        bf16x8 kf2, vf02, vf12;
        if (jt + 32 < jrange) {   // prefetch next tile
            kf2  = *(const bf16x8*)&kbase[(size_t)(jn + l31) * RC_ + hi * 8];
            vf02 = *(const bf16x8*)&vbase[jn + hi * 8];
            vf12 = *(const bf16x8*)&vbase[jn + 16 + hi * 8];
        }

        f32x16 z;
#pragma unroll
        for (int r = 0; r < 16; ++r) z[r] = 0.f;
        f32x16 d = __builtin_amdgcn_mfma_f32_32x32x16_bf16(kf, qf, z, 0, 0, 0);
        // d[r] = S[i = l31][ j = (jt) + (r&3)+8*(r>>2)+4*hi ]  (log2 domain)

        // tile row-max
        float tm = d[0];
#pragma unroll
        for (int r = 1; r < 16; ++r) tm = fmaxf(tm, d[r]);
        tm = fmaxf(tm, __shfl_xor(tm, 32));

        if (__any(tm > m)) {
            float nm = fmaxf(m, tm);
            float al = exp2f(m - nm);
            m = nm; l *= al;
#pragma unroll
            for (int r = 0; r < 16; ++r) o[r] *= al;
        }

        float p[16]; float ps = 0.f;
#pragma unroll
        for (int r = 0; r < 16; ++r) { p[r] = exp2f(d[r] - m); ps += p[r]; }
        l += ps + __shfl_xor(ps, 32);

        // pack p into bf16 pairs: W[w] = (p[2w], p[2w+1])
        u32 W[8];
#pragma unroll
        for (int w = 0; w < 8; ++w)
            W[w] = (u32)f2bf(p[2 * w]) | ((u32)f2bf(p[2 * w + 1]) << 16);
        // partner values (lane ^ 32)
        u32 PW[8];
#pragma unroll
        for (int w = 0; w < 8; ++w)
            PW[w] = (u32)__shfl_xor((int)W[w], 32);

        // PV A-frags (j k-slots of 16)
        u32 fa[4], fb[4];
        fa[0] = hi ? PW[2] : W[0];  fa[1] = hi ? PW[3] : W[1];
        fa[2] = hi ? W[2] : PW[0];  fa[3] = hi ? W[3] : PW[1];
        fb[0] = hi ? PW[6] : W[4];  fb[1] = hi ? PW[7] : W[5];
        fb[2] = hi ? W[6] : PW[4];  fb[3] = hi ? W[7] : PW[5];

        o = __builtin_amdgcn_mfma_f32_32x32x16_bf16(*(bf16x8*)fa, vf0, o, 0, 0, 0);
        o = __builtin_amdgcn_mfma_f32_32x32x16_bf16(*(bf16x8*)fb, vf1, o, 0, 0, 0);

        kf = kf2; vf0 = vf02; vf1 = vf12;
    }

    // store partials. lane holds: rc = l31 (valid < 16), i = 8*(r>>2) + 4*hi + (r&3)
    if (l31 < 16) {
        size_t base = ((size_t)(b * JS + js) * RC_ + l31) * N_ + i0;
#pragma unroll
        for (int qd = 0; qd < 4; ++qd) {
            float4 st = {o[4 * qd + 0], o[4 * qd + 1], o[4 * qd + 2], o[4 * qd + 3]};
            *(float4*)&opart[base + 8 * qd + 4 * hi] = st;
        }
    }
    if (hi == 0) {
        mpart[(size_t)(b * JS + js) * N_ + i0 + l31] = m;
        lpart[(size_t)(b * JS + js) * N_ + i0 + l31] = l;
    }
}

// ---------------------------------------------------------------- K3b: merge j-split partials
__global__ __launch_bounds__(256) void k_amerge(
        const float* __restrict__ opart, const float* __restrict__ mpart,
        const float* __restrict__ lpart, float* __restrict__ aoT, int JS) {
    int gid = blockIdx.x * 256 + threadIdx.x;   // 131072 total
    int i  = gid & 4095;
    int t2 = gid >> 12;          // 0..31
    int b  = t2 >> 2;
    int rg = t2 & 3;

    float M = -1e30f;
    for (int js = 0; js < JS; ++js)
        M = fmaxf(M, mpart[(size_t)(b * JS + js) * N_ + i]);
    float w[16];
    float L = 0.f;
    for (int js = 0; js < JS; ++js) {
        float mv = mpart[(size_t)(b * JS + js) * N_ + i];
        float lv = lpart[(size_t)(b * JS + js) * N_ + i];
        w[js] = exp2f(mv - M);
        L = fmaf(lv, w[js], L);
    }
    float inv = 1.f / L;
    float out[4] = {0.f, 0.f, 0.f, 0.f};
    for (int js = 0; js < JS; ++js) {
        size_t base = ((size_t)(b * JS + js) * RC_ + rg * 4) * N_ + i;
#pragma unroll
        for (int r = 0; r < 4; ++r)
            out[r] = fmaf(opart[base + (size_t)r * N_], w[js], out[r]);
    }
    float4 res = {out[0] * inv, out[1] * inv, out[2] * inv, out[3] * inv};
    *(float4*)&aoT[((size_t)(b * N_ + i) * RC_) + rg * 4] = res;
}

// ---------------------------------------------------------------- K4: proj (RC->C) + residual
__global__ __launch_bounds__(256) void k_proj(
        const float* __restrict__ x, const float* __restrict__ pw,
        const float* __restrict__ pb, const float* __restrict__ aoT,
        float* __restrict__ out) {
    int ch = blockIdx.x % 6;
    int t  = blockIdx.x / 6;
    int ntile = t & 15;
    int b = t >> 4;
    int n = ntile * 256 + threadIdx.x;

    const float4* a4 = (const float4*)&aoT[(size_t)(b * N_ + n) * RC_];
    float4 A0 = a4[0], A1 = a4[1], A2 = a4[2], A3 = a4[3];
    float av[16] = {A0.x, A0.y, A0.z, A0.w, A1.x, A1.y, A1.z, A1.w,
                    A2.x, A2.y, A2.z, A2.w, A3.x, A3.y, A3.z, A3.w};

    __shared__ float plds[128 * 16];
    __shared__ float pblds[128];
    int c0 = ch * 128;
    for (int idx = threadIdx.x; idx < 2048; idx += 256)
        plds[idx] = pw[(size_t)c0 * 16 + idx];
    if (threadIdx.x < 128) pblds[threadIdx.x] = pb[c0 + threadIdx.x];
    __syncthreads();

    for (int cc = 0; cc < 128; ++cc) {
        size_t xi = ((size_t)(b * 768 + c0 + cc)) * N_ + n;
        const float* wp = &plds[cc * 16];
        float t0 = fmaf(av[0],  wp[0],  pblds[cc] + x[xi]);
        float t1 = fmaf(av[1],  wp[1],  0.f);
        float t2 = fmaf(av[2],  wp[2],  0.f);
        float t3 = fmaf(av[3],  wp[3],  0.f);
#pragma unroll
        for (int r = 4; r < 16; r += 4) {
            t0 = fmaf(av[r + 0], wp[r + 0], t0);
            t1 = fmaf(av[r + 1], wp[r + 1], t1);
            t2 = fmaf(av[r + 2], wp[r + 2], t2);
            t3 = fmaf(av[r + 3], wp[r + 3], t3);
        }
        out[xi] = (t0 + t1) + (t2 + t3);
    }
}

// ---------------------------------------------------------------- launch
extern "C" void kernel_launch(void* const* d_in, const int* in_sizes, int n_in,
                              void* d_out, int out_size, void* d_ws, size_t ws_size,
                              hipStream_t stream) {
    const float* x    = (const float*)d_in[0];
    const float* gn_w = (const float*)d_in[1];
    const float* gn_b = (const float*)d_in[2];
    const float* qw   = (const float*)d_in[3];
    const float* qb   = (const float*)d_in[4];
    const float* kw   = (const float*)d_in[5];
    const float* kb   = (const float*)d_in[6];
    const float* vw   = (const float*)d_in[7];
    const float* vb   = (const float*)d_in[8];
    const float* pw   = (const float*)d_in[9];
    const float* pb   = (const float*)d_in[10];
    float* out = (float*)d_out;
    float* wsf = (float*)d_ws;

    size_t avail = ws_size / 4;   // floats
    int JS = 8;
    while (JS > 1) {
        size_t need = (size_t)OFF_PART + (size_t)JS * ((size_t)B_ * RC_ * N_ + 2 * (size_t)B_ * N_);
        if (need <= avail) break;
        JS >>= 1;
    }
    int jrange = N_ / JS;

    float* aoT = wsf + OFF_AO;
    const ushort_t* qB  = (const ushort_t*)(wsf + OFF_QB);
    const ushort_t* kB  = (const ushort_t*)(wsf + OFF_KB);
    const ushort_t* vBt = (const ushort_t*)(wsf + OFF_VB);
    float* opart = wsf + OFF_PART;
    float* mpart = opart + (size_t)B_ * JS * RC_ * N_;
    float* lpart = mpart + (size_t)B_ * JS * N_;

    k_zero<<<1, 64, 0, stream>>>(wsf);
    k_stats<<<16 * 128, 256, 0, stream>>>(x, wsf);
    k_qkv<<<B_ * 64, 256, 0, stream>>>(x, gn_w, gn_b, qw, qb, kw, kb, vw, vb, wsf);
    k_attn<<<B_ * 32 * JS, 256, 0, stream>>>(qB, kB, vBt, opart, mpart, lpart, JS, jrange);
    k_amerge<<<512, 256, 0, stream>>>(opart, mpart, lpart, aoT, JS);
    k_proj<<<B_ * 16 * 6, 256, 0, stream>>>(x, pw, pb, aoT, out);
}

// Round 8
// 360.918 us; speedup vs baseline: 2.2695x; 1.0587x over previous
//
#include <hip/hip_runtime.h>
#include <hip/hip_bf16.h>
#include <math.h>

// Problem constants
#define B_    8
#define C_    768
#define N_    4096          // H*W = 64*64
#define RC_   16
#define CPG_  384           // channels per group (2 groups)
#define GCNT  ((size_t)CPG_ * N_)   // elements per (b,group) = 1572864
#define EPSV  1e-6f
#define LOG2E 1.4426950408889634f
#define SCALE 0.25f         // RC^-0.5
#define QPRE  (SCALE * LOG2E)

// ws layout (floats):
//   [0,32)     : group stats (16 x {sum,sumsq})
//   OFF_B2     : bias2 f32 [B][48]
//   OFF_W2     : w2 f32 [B][768][48]  (GN folded into conv weights)
//   OFF_AO     : aoT f32 [B][N][16]
//   OFF_QB/KB  : qB,kB bf16 [B][N][16] (q pre-scaled by QPRE)
//   OFF_VB     : vBt bf16 [B][16][N]
//   OFF_PART   : opart[b][js][rc][n] f32, mpart, lpart
#define OFF_B2   32
#define OFF_W2   (OFF_B2 + B_*48)
#define OFF_AO   (OFF_W2 + B_*C_*48)
#define AO_SZ    (B_*N_*RC_)
#define OFF_QB   (OFF_AO + AO_SZ)
#define QB_SZF   (B_*N_*RC_/2)
#define OFF_KB   (OFF_QB + QB_SZF)
#define OFF_VB   (OFF_KB + QB_SZF)
#define OFF_PART (OFF_VB + QB_SZF)

typedef __attribute__((ext_vector_type(8)))  short bf16x8;
typedef __attribute__((ext_vector_type(16))) float f32x16;
typedef unsigned int  u32;
typedef unsigned short ushort_t;

__device__ inline ushort_t f2bf(float f) {
    __hip_bfloat16 h = __float2bfloat16(f);
    return *reinterpret_cast<ushort_t*>(&h);
}

// ---------------------------------------------------------------- K0: zero stats
__global__ void k_zero(float* ws) {
    if (threadIdx.x < 32) ws[threadIdx.x] = 0.f;
}

// ---------------------------------------------------------------- K1: GN stats
__global__ __launch_bounds__(256) void k_stats(const float* __restrict__ x,
                                               float* __restrict__ ws) {
    const int SB = 128;
    int seg = blockIdx.x / SB;      // b*2+g
    int blk = blockIdx.x % SB;
    const float4* xs = (const float4*)(x + (size_t)seg * GCNT);
    int idx = blk * 256 + threadIdx.x;
    float s = 0.f, ss = 0.f;
#pragma unroll
    for (int it = 0; it < 12; ++it) {
        float4 v = xs[idx + it * (SB * 256)];
        s  += (v.x + v.y) + (v.z + v.w);
        ss += (v.x*v.x + v.y*v.y) + (v.z*v.z + v.w*v.w);
    }
    for (int off = 32; off; off >>= 1) {
        s  += __shfl_down(s, off);
        ss += __shfl_down(ss, off);
    }
    __shared__ float ps[4], pss[4];
    int wid = threadIdx.x >> 6, lane = threadIdx.x & 63;
    if (lane == 0) { ps[wid] = s; pss[wid] = ss; }
    __syncthreads();
    if (threadIdx.x == 0) {
        float a = (ps[0] + ps[1]) + (ps[2] + ps[3]);
        float b = (pss[0] + pss[1]) + (pss[2] + pss[3]);
        atomicAdd(&ws[seg * 2 + 0], a);
        atomicAdd(&ws[seg * 2 + 1], b);
    }
}

// ---------------------------------------------------------------- K1b: fold GN into weights
// thread per (b,c): w2[b][c][m] = sel_w[m][c] * a_c  (q rows also * QPRE)
__global__ __launch_bounds__(256) void k_fold(
        const float* __restrict__ gn_w,
        const float* __restrict__ qw, const float* __restrict__ kw,
        const float* __restrict__ vw, float* __restrict__ ws) {
    int gid = blockIdx.x * 256 + threadIdx.x;   // 6144
    int b = gid / C_, c = gid % C_;
    int g = (c >= CPG_) ? 1 : 0;
    const float cntinv = 1.f / (float)GCNT;
    float sum  = ws[(b * 2 + g) * 2 + 0];
    float ssum = ws[(b * 2 + g) * 2 + 1];
    float mean = sum * cntinv;
    float var  = ssum * cntinv - mean * mean;
    float rstd = rsqrtf(var + EPSV);
    float a = rstd * gn_w[c];
    float* w2 = ws + OFF_W2 + ((size_t)b * C_ + c) * 48;
#pragma unroll
    for (int m = 0; m < 16; ++m) w2[m]      = qw[m * C_ + c] * a * QPRE;
#pragma unroll
    for (int m = 0; m < 16; ++m) w2[16 + m] = kw[m * C_ + c] * a;
#pragma unroll
    for (int m = 0; m < 16; ++m) w2[32 + m] = vw[m * C_ + c] * a;
}

// ---------------------------------------------------------------- K1c: fold GN into bias
// wave per (b,m): bias2[b][m] = orig_b[m] + sum_c w[m][c]*(beta_c - mean*a_c)
__global__ __launch_bounds__(256) void k_bias(
        const float* __restrict__ gn_w, const float* __restrict__ gn_b,
        const float* __restrict__ qw, const float* __restrict__ qb,
        const float* __restrict__ kw, const float* __restrict__ kb,
        const float* __restrict__ vw, const float* __restrict__ vb,
        float* __restrict__ ws) {
    int wid = blockIdx.x * 4 + (threadIdx.x >> 6);   // 0..383
    int lane = threadIdx.x & 63;
    int b = wid / 48, m = wid % 48;
    const float cntinv = 1.f / (float)GCNT;
    float mean0 = ws[(b * 2 + 0) * 2] * cntinv;
    float mean1 = ws[(b * 2 + 1) * 2] * cntinv;
    float var0  = ws[(b * 2 + 0) * 2 + 1] * cntinv - mean0 * mean0;
    float var1  = ws[(b * 2 + 1) * 2 + 1] * cntinv - mean1 * mean1;
    float rstd0 = rsqrtf(var0 + EPSV), rstd1 = rsqrtf(var1 + EPSV);

    const float* wrow = (m < 16) ? (qw + m * C_) : (m < 32) ? (kw + (m - 16) * C_)
                                                            : (vw + (m - 32) * C_);
    float s = 0.f;
#pragma unroll
    for (int k = 0; k < 12; ++k) {
        int c = lane + k * 64;
        float mean = (c < CPG_) ? mean0 : mean1;
        float rstd = (c < CPG_) ? rstd0 : rstd1;
        float a = rstd * gn_w[c];
        s = fmaf(wrow[c], gn_b[c] - mean * a, s);
    }
    for (int off = 32; off; off >>= 1) s += __shfl_down(s, off);
    if (lane == 0) {
        float base = (m < 16) ? qb[m] : (m < 32) ? kb[m - 16] : vb[m - 32];
        float tot = base + s;
        if (m < 16) tot *= QPRE;
        ws[OFF_B2 + b * 48 + m] = tot;
    }
}

// ---------------------------------------------------------------- K2: qkv conv (GN pre-folded)
// grid 512 blocks x 512 thr (8 waves). Wave = (b, ntile64) x c-chunk-of-96.
// All 48 outputs per lane in registers; weights via wave-uniform scalar loads.
__global__ __launch_bounds__(512) void k_qkv(
        const float* __restrict__ x, float* __restrict__ ws) {
    int b = blockIdx.x >> 6;
    int ntile = blockIdx.x & 63;
    int wv = threadIdx.x >> 6;                               // 0..7
    int wu = __builtin_amdgcn_readfirstlane(wv);             // force SGPR
    int lane = threadIdx.x & 63;
    int n = ntile * 64 + lane;

    const float* xp = x + ((size_t)b * C_ + wu * 96) * N_ + n;
    const float* wp = ws + OFF_W2 + ((size_t)b * C_ + wu * 96) * 48;

    float acc[48];
#pragma unroll
    for (int m = 0; m < 48; ++m) acc[m] = 0.f;

#pragma unroll 2
    for (int cc = 0; cc < 96; ++cc) {
        float xv = xp[(size_t)cc * N_];
        const float4* wr4 = (const float4*)(wp + cc * 48);
#pragma unroll
        for (int j = 0; j < 12; ++j) {
            float4 w4 = wr4[j];
            acc[j * 4 + 0] = fmaf(xv, w4.x, acc[j * 4 + 0]);
            acc[j * 4 + 1] = fmaf(xv, w4.y, acc[j * 4 + 1]);
            acc[j * 4 + 2] = fmaf(xv, w4.z, acc[j * 4 + 2]);
            acc[j * 4 + 3] = fmaf(xv, w4.w, acc[j * 4 + 3]);
        }
    }

    // two-pass cross-wave reduce (4 waves per pass, 48 KiB LDS)
    __shared__ float red[4 * 48 * 64];
    int n_r = threadIdx.x & 63;
    int mb  = threadIdx.x >> 6;    // 0..7
    float fin[6];

    if (wv < 4) {
#pragma unroll
        for (int m = 0; m < 48; ++m) red[(wv * 48 + m) * 64 + lane] = acc[m];
    }
    __syncthreads();
#pragma unroll
    for (int k = 0; k < 6; ++k) {
        int m = k * 8 + mb;
        fin[k] = (red[(0 * 48 + m) * 64 + n_r] + red[(1 * 48 + m) * 64 + n_r])
               + (red[(2 * 48 + m) * 64 + n_r] + red[(3 * 48 + m) * 64 + n_r]);
    }
    __syncthreads();
    if (wv >= 4) {
#pragma unroll
        for (int m = 0; m < 48; ++m) red[((wv - 4) * 48 + m) * 64 + lane] = acc[m];
    }
    __syncthreads();
#pragma unroll
    for (int k = 0; k < 6; ++k) {
        int m = k * 8 + mb;
        fin[k] += (red[(0 * 48 + m) * 64 + n_r] + red[(1 * 48 + m) * 64 + n_r])
                + (red[(2 * 48 + m) * 64 + n_r] + red[(3 * 48 + m) * 64 + n_r]);
    }

    // epilogue: add folded bias, convert, store
    ushort_t* qB  = (ushort_t*)(ws + OFF_QB);
    ushort_t* kB  = (ushort_t*)(ws + OFF_KB);
    ushort_t* vBt = (ushort_t*)(ws + OFF_VB);
    int nn = ntile * 64 + n_r;
    size_t nb = (size_t)(b * N_ + nn) * RC_;
#pragma unroll
    for (int k = 0; k < 6; ++k) {
        int m = k * 8 + mb;
        float v = fin[k] + ws[OFF_B2 + b * 48 + m];
        if (m < 16)      qB[nb + m]        = f2bf(v);
        else if (m < 32) kB[nb + (m - 16)] = f2bf(v);
        else             vBt[((size_t)b * RC_ + (m - 32)) * N_ + nn] = f2bf(v);
    }
}

// ---------------------------------------------------------------- K3: MFMA flash attention
// grid: ((b*32 + itile)*JS + js), 256 threads = 4 waves, each wave owns 32 i-rows.
__global__ __launch_bounds__(256) void k_attn(
        const ushort_t* __restrict__ qB, const ushort_t* __restrict__ kB,
        const ushort_t* __restrict__ vBt,
        float* __restrict__ opart, float* __restrict__ mpart, float* __restrict__ lpart,
        int JS, int jrange) {
    int js = blockIdx.x % JS;
    int t  = blockIdx.x / JS;
    int itile = t & 31;
    int b = t >> 5;
    int wave = threadIdx.x >> 6;
    int lane = threadIdx.x & 63;
    int hi   = lane >> 5;
    int l31  = lane & 31;
    int i0 = itile * 128 + wave * 32;
    int rcv = (l31 < 16) ? l31 : 15;   // clamp (cols 16-31 unused)

    bf16x8 qf = *(const bf16x8*)&qB[((size_t)b * N_ + i0 + l31) * RC_ + hi * 8];

    f32x16 o;
#pragma unroll
    for (int r = 0; r < 16; ++r) o[r] = 0.f;
    float m = -1e30f, l = 0.f;

    int j0 = js * jrange;
    const ushort_t* kbase = kB + (size_t)b * N_ * RC_;
    const ushort_t* vbase = vBt + ((size_t)b * RC_ + rcv) * N_;

    bf16x8 kf  = *(const bf16x8*)&kbase[(size_t)(j0 + l31) * RC_ + hi * 8];
    bf16x8 vf0 = *(const bf16x8*)&vbase[j0 + hi * 8];
    bf16x8 vf1 = *(const bf16x8*)&vbase[j0 + 16 + hi * 8];

    for (int jt = 0; jt < jrange; jt += 32) {
        int jn = j0 + jt + 32;
        bf16x8 kf2, vf02, vf12;
        if (jt + 32 < jrange) {
            kf2  = *(const bf16x8*)&kbase[(size_t)(jn + l31) * RC_ + hi * 8];
            vf02 = *(const bf16x8*)&vbase[jn + hi * 8];
            vf12 = *(const bf16x8*)&vbase[jn + 16 + hi * 8];
        }

        f32x16 z;
#pragma unroll
        for (int r = 0; r < 16; ++r) z[r] = 0.f;
        f32x16 d = __builtin_amdgcn_mfma_f32_32x32x16_bf16(kf, qf, z, 0, 0, 0);

        float tm = d[0];
#pragma unroll
        for (int r = 1; r < 16; ++r) tm = fmaxf(tm, d[r]);
        tm = fmaxf(tm, __shfl_xor(tm, 32));

        if (__any(tm > m)) {
            float nm = fmaxf(m, tm);
            float al = exp2f(m - nm);
            m = nm; l *= al;
#pragma unroll
            for (int r = 0; r < 16; ++r) o[r] *= al;
        }

        float p[16]; float ps = 0.f;
#pragma unroll
        for (int r = 0; r < 16; ++r) { p[r] = exp2f(d[r] - m); ps += p[r]; }
        l += ps + __shfl_xor(ps, 32);

        u32 W[8];
#pragma unroll
        for (int w = 0; w < 8; ++w)
            W[w] = (u32)f2bf(p[2 * w]) | ((u32)f2bf(p[2 * w + 1]) << 16);
        u32 PW[8];
#pragma unroll
        for (int w = 0; w < 8; ++w)
            PW[w] = (u32)__shfl_xor((int)W[w], 32);

        u32 fa[4], fb[4];
        fa[0] = hi ? PW[2] : W[0];  fa[1] = hi ? PW[3] : W[1];
        fa[2] = hi ? W[2] : PW[0];  fa[3] = hi ? W[3] : PW[1];
        fb[0] = hi ? PW[6] : W[4];  fb[1] = hi ? PW[7] : W[5];
        fb[2] = hi ? W[6] : PW[4];  fb[3] = hi ? W[7] : PW[5];

        o = __builtin_amdgcn_mfma_f32_32x32x16_bf16(*(bf16x8*)fa, vf0, o, 0, 0, 0);
        o = __builtin_amdgcn_mfma_f32_32x32x16_bf16(*(bf16x8*)fb, vf1, o, 0, 0, 0);

        kf = kf2; vf0 = vf02; vf1 = vf12;
    }

    if (l31 < 16) {
        size_t base = ((size_t)(b * JS + js) * RC_ + l31) * N_ + i0;
#pragma unroll
        for (int qd = 0; qd < 4; ++qd) {
            float4 st = {o[4 * qd + 0], o[4 * qd + 1], o[4 * qd + 2], o[4 * qd + 3]};
            *(float4*)&opart[base + 8 * qd + 4 * hi] = st;
        }
    }
    if (hi == 0) {
        mpart[(size_t)(b * JS + js) * N_ + i0 + l31] = m;
        lpart[(size_t)(b * JS + js) * N_ + i0 + l31] = l;
    }
}

// ---------------------------------------------------------------- K3b: merge j-split partials
__global__ __launch_bounds__(256) void k_amerge(
        const float* __restrict__ opart, const float* __restrict__ mpart,
        const float* __restrict__ lpart, float* __restrict__ aoT, int JS) {
    int gid = blockIdx.x * 256 + threadIdx.x;   // 131072
    int i  = gid & 4095;
    int t2 = gid >> 12;
    int b  = t2 >> 2;
    int rg = t2 & 3;

    float M = -1e30f;
    for (int js = 0; js < JS; ++js)
        M = fmaxf(M, mpart[(size_t)(b * JS + js) * N_ + i]);
    float w[16];
    float L = 0.f;
    for (int js = 0; js < JS; ++js) {
        float mv = mpart[(size_t)(b * JS + js) * N_ + i];
        float lv = lpart[(size_t)(b * JS + js) * N_ + i];
        w[js] = exp2f(mv - M);
        L = fmaf(lv, w[js], L);
    }
    float inv = 1.f / L;
    float out[4] = {0.f, 0.f, 0.f, 0.f};
    for (int js = 0; js < JS; ++js) {
        size_t base = ((size_t)(b * JS + js) * RC_ + rg * 4) * N_ + i;
#pragma unroll
        for (int r = 0; r < 4; ++r)
            out[r] = fmaf(opart[base + (size_t)r * N_], w[js], out[r]);
    }
    float4 res = {out[0] * inv, out[1] * inv, out[2] * inv, out[3] * inv};
    *(float4*)&aoT[((size_t)(b * N_ + i) * RC_) + rg * 4] = res;
}

// ---------------------------------------------------------------- K4: proj (RC->C) + residual
// grid: (b*16 + ntile)*12 + cchunk, 64 channels per block.
__global__ __launch_bounds__(256) void k_proj(
        const float* __restrict__ x, const float* __restrict__ pw,
        const float* __restrict__ pb, const float* __restrict__ aoT,
        float* __restrict__ out) {
    int ch = blockIdx.x % 12;
    int t  = blockIdx.x / 12;
    int ntile = t & 15;
    int b = t >> 4;
    int n = ntile * 256 + threadIdx.x;

    const float4* a4 = (const float4*)&aoT[(size_t)(b * N_ + n) * RC_];
    float4 A0 = a4[0], A1 = a4[1], A2 = a4[2], A3 = a4[3];
    float av[16] = {A0.x, A0.y, A0.z, A0.w, A1.x, A1.y, A1.z, A1.w,
                    A2.x, A2.y, A2.z, A2.w, A3.x, A3.y, A3.z, A3.w};

    __shared__ float plds[64 * 16];
    __shared__ float pblds[64];
    int c0 = ch * 64;
    for (int idx = threadIdx.x; idx < 1024; idx += 256)
        plds[idx] = pw[(size_t)c0 * 16 + idx];
    if (threadIdx.x < 64) pblds[threadIdx.x] = pb[c0 + threadIdx.x];
    __syncthreads();

    for (int cc = 0; cc < 64; ++cc) {
        size_t xi = ((size_t)(b * 768 + c0 + cc)) * N_ + n;
        const float* wp = &plds[cc * 16];
        float t0 = fmaf(av[0],  wp[0],  pblds[cc] + x[xi]);
        float t1 = fmaf(av[1],  wp[1],  0.f);
        float t2 = fmaf(av[2],  wp[2],  0.f);
        float t3 = fmaf(av[3],  wp[3],  0.f);
#pragma unroll
        for (int r = 4; r < 16; r += 4) {
            t0 = fmaf(av[r + 0], wp[r + 0], t0);
            t1 = fmaf(av[r + 1], wp[r + 1], t1);
            t2 = fmaf(av[r + 2], wp[r + 2], t2);
            t3 = fmaf(av[r + 3], wp[r + 3], t3);
        }
        out[xi] = (t0 + t1) + (t2 + t3);
    }
}

// ---------------------------------------------------------------- launch
extern "C" void kernel_launch(void* const* d_in, const int* in_sizes, int n_in,
                              void* d_out, int out_size, void* d_ws, size_t ws_size,
                              hipStream_t stream) {
    const float* x    = (const float*)d_in[0];
    const float* gn_w = (const float*)d_in[1];
    const float* gn_b = (const float*)d_in[2];
    const float* qw   = (const float*)d_in[3];
    const float* qb   = (const float*)d_in[4];
    const float* kw   = (const float*)d_in[5];
    const float* kb   = (const float*)d_in[6];
    const float* vw   = (const float*)d_in[7];
    const float* vb   = (const float*)d_in[8];
    const float* pw   = (const float*)d_in[9];
    const float* pb   = (const float*)d_in[10];
    float* out = (float*)d_out;
    float* wsf = (float*)d_ws;

    size_t avail = ws_size / 4;   // floats
    int JS = 8;
    while (JS > 1) {
        size_t need = (size_t)OFF_PART + (size_t)JS * ((size_t)B_ * RC_ * N_ + 2 * (size_t)B_ * N_);
        if (need <= avail) break;
        JS >>= 1;
    }
    int jrange = N_ / JS;

    float* aoT = wsf + OFF_AO;
    const ushort_t* qB  = (const ushort_t*)(wsf + OFF_QB);
    const ushort_t* kB  = (const ushort_t*)(wsf + OFF_KB);
    const ushort_t* vBt = (const ushort_t*)(wsf + OFF_VB);
    float* opart = wsf + OFF_PART;
    float* mpart = opart + (size_t)B_ * JS * RC_ * N_;
    float* lpart = mpart + (size_t)B_ * JS * N_;

    k_zero<<<1, 64, 0, stream>>>(wsf);
    k_stats<<<16 * 128, 256, 0, stream>>>(x, wsf);
    k_fold<<<24, 256, 0, stream>>>(gn_w, qw, kw, vw, wsf);
    k_bias<<<96, 256, 0, stream>>>(gn_w, gn_b, qw, qb, kw, kb, vw, vb, wsf);
    k_qkv<<<B_ * 64, 512, 0, stream>>>(x, wsf);
    k_attn<<<B_ * 32 * JS, 256, 0, stream>>>(qB, kB, vBt, opart, mpart, lpart, JS, jrange);
    k_amerge<<<512, 256, 0, stream>>>(opart, mpart, lpart, aoT, JS);
    k_proj<<<B_ * 16 * 12, 256, 0, stream>>>(x, pw, pb, aoT, out);
}

// Round 9
// 349.656 us; speedup vs baseline: 2.3426x; 1.0322x over previous
//
#include <hip/hip_runtime.h>
#include <hip/hip_bf16.h>
#include <math.h>

// Problem constants
#define B_    8
#define C_    768
#define N_    4096          // H*W = 64*64
#define RC_   16
#define CPG_  384           // channels per group (2 groups)
#define GCNT  ((size_t)CPG_ * N_)   // elements per (b,group) = 1572864
#define EPSV  1e-6f
#define LOG2E 1.4426950408889634f
#define SCALE 0.25f         // RC^-0.5
#define QPRE  (SCALE * LOG2E)

// ws layout (floats):
//   [0,32)     : group stats (16 x {sum,sumsq})
//   OFF_B2     : bias2 f32 [B][48]
//   OFF_W2     : w2 f32 [B][768][48]  (GN folded into conv weights)
//   OFF_AO     : aoT f32 [B][N][16]
//   OFF_QB/KB  : qB,kB bf16 [B][N][16] (q pre-scaled by QPRE)
//   OFF_VB     : vBt bf16 [B][16][N]
//   OFF_ONES   : bf16 ones[N]  (PV l-column)
//   OFF_PART   : opart[b][js][rc][n] f32, mpart, lpart
#define OFF_B2   32
#define OFF_W2   (OFF_B2 + B_*48)
#define OFF_AO   (OFF_W2 + B_*C_*48)
#define AO_SZ    (B_*N_*RC_)
#define OFF_QB   (OFF_AO + AO_SZ)
#define QB_SZF   (B_*N_*RC_/2)
#define OFF_KB   (OFF_QB + QB_SZF)
#define OFF_VB   (OFF_KB + QB_SZF)
#define OFF_ONES (OFF_VB + QB_SZF)
#define OFF_PART (OFF_ONES + N_/2)

typedef __attribute__((ext_vector_type(8)))  short bf16x8;
typedef __attribute__((ext_vector_type(16))) float f32x16;
typedef unsigned int  u32;
typedef unsigned short ushort_t;

__device__ inline ushort_t f2bf(float f) {
    __hip_bfloat16 h = __float2bfloat16(f);
    return *reinterpret_cast<ushort_t*>(&h);
}
__device__ inline u32 cvt_pk_bf16(float lo, float hi) {
    u32 r;
    asm("v_cvt_pk_bf16_f32 %0, %1, %2" : "=v"(r) : "v"(lo), "v"(hi));
    return r;
}

// ---------------------------------------------------------------- K0: init (stats=0, ones=1.0bf16)
__global__ __launch_bounds__(256) void k_init(float* ws) {
    int gid = blockIdx.x * 256 + threadIdx.x;
    if (gid < 32) ws[gid] = 0.f;
    if (gid < N_ / 2) ((u32*)(ws + OFF_ONES))[gid] = 0x3F803F80u;
}

// ---------------------------------------------------------------- K1: GN stats
__global__ __launch_bounds__(256) void k_stats(const float* __restrict__ x,
                                               float* __restrict__ ws) {
    const int SB = 128;
    int seg = blockIdx.x / SB;      // b*2+g
    int blk = blockIdx.x % SB;
    const float4* xs = (const float4*)(x + (size_t)seg * GCNT);
    int idx = blk * 256 + threadIdx.x;
    float s = 0.f, ss = 0.f;
#pragma unroll
    for (int it = 0; it < 12; ++it) {
        float4 v = xs[idx + it * (SB * 256)];
        s  += (v.x + v.y) + (v.z + v.w);
        ss += (v.x*v.x + v.y*v.y) + (v.z*v.z + v.w*v.w);
    }
    for (int off = 32; off; off >>= 1) {
        s  += __shfl_down(s, off);
        ss += __shfl_down(ss, off);
    }
    __shared__ float ps[4], pss[4];
    int wid = threadIdx.x >> 6, lane = threadIdx.x & 63;
    if (lane == 0) { ps[wid] = s; pss[wid] = ss; }
    __syncthreads();
    if (threadIdx.x == 0) {
        float a = (ps[0] + ps[1]) + (ps[2] + ps[3]);
        float b = (pss[0] + pss[1]) + (pss[2] + pss[3]);
        atomicAdd(&ws[seg * 2 + 0], a);
        atomicAdd(&ws[seg * 2 + 1], b);
    }
}

// ---------------------------------------------------------------- K1b: fold GN into weights
__global__ __launch_bounds__(256) void k_fold(
        const float* __restrict__ gn_w,
        const float* __restrict__ qw, const float* __restrict__ kw,
        const float* __restrict__ vw, float* __restrict__ ws) {
    int gid = blockIdx.x * 256 + threadIdx.x;   // 6144
    int b = gid / C_, c = gid % C_;
    int g = (c >= CPG_) ? 1 : 0;
    const float cntinv = 1.f / (float)GCNT;
    float sum  = ws[(b * 2 + g) * 2 + 0];
    float ssum = ws[(b * 2 + g) * 2 + 1];
    float mean = sum * cntinv;
    float var  = ssum * cntinv - mean * mean;
    float rstd = rsqrtf(var + EPSV);
    float a = rstd * gn_w[c];
    float* w2 = ws + OFF_W2 + ((size_t)b * C_ + c) * 48;
#pragma unroll
    for (int m = 0; m < 16; ++m) w2[m]      = qw[m * C_ + c] * a * QPRE;
#pragma unroll
    for (int m = 0; m < 16; ++m) w2[16 + m] = kw[m * C_ + c] * a;
#pragma unroll
    for (int m = 0; m < 16; ++m) w2[32 + m] = vw[m * C_ + c] * a;
}

// ---------------------------------------------------------------- K1c: fold GN into bias
__global__ __launch_bounds__(256) void k_bias(
        const float* __restrict__ gn_w, const float* __restrict__ gn_b,
        const float* __restrict__ qw, const float* __restrict__ qb,
        const float* __restrict__ kw, const float* __restrict__ kb,
        const float* __restrict__ vw, const float* __restrict__ vb,
        float* __restrict__ ws) {
    int wid = blockIdx.x * 4 + (threadIdx.x >> 6);   // 0..383
    int lane = threadIdx.x & 63;
    int b = wid / 48, m = wid % 48;
    const float cntinv = 1.f / (float)GCNT;
    float mean0 = ws[(b * 2 + 0) * 2] * cntinv;
    float mean1 = ws[(b * 2 + 1) * 2] * cntinv;
    float var0  = ws[(b * 2 + 0) * 2 + 1] * cntinv - mean0 * mean0;
    float var1  = ws[(b * 2 + 1) * 2 + 1] * cntinv - mean1 * mean1;
    float rstd0 = rsqrtf(var0 + EPSV), rstd1 = rsqrtf(var1 + EPSV);

    const float* wrow = (m < 16) ? (qw + m * C_) : (m < 32) ? (kw + (m - 16) * C_)
                                                            : (vw + (m - 32) * C_);
    float s = 0.f;
#pragma unroll
    for (int k = 0; k < 12; ++k) {
        int c = lane + k * 64;
        float mean = (c < CPG_) ? mean0 : mean1;
        float rstd = (c < CPG_) ? rstd0 : rstd1;
        float a = rstd * gn_w[c];
        s = fmaf(wrow[c], gn_b[c] - mean * a, s);
    }
    for (int off = 32; off; off >>= 1) s += __shfl_down(s, off);
    if (lane == 0) {
        float base = (m < 16) ? qb[m] : (m < 32) ? kb[m - 16] : vb[m - 32];
        float tot = base + s;
        if (m < 16) tot *= QPRE;
        ws[OFF_B2 + b * 48 + m] = tot;
    }
}

// ---------------------------------------------------------------- K2: qkv conv (GN pre-folded)
__global__ __launch_bounds__(512) void k_qkv(
        const float* __restrict__ x, float* __restrict__ ws) {
    int b = blockIdx.x >> 6;
    int ntile = blockIdx.x & 63;
    int wv = threadIdx.x >> 6;                               // 0..7
    int wu = __builtin_amdgcn_readfirstlane(wv);             // force SGPR
    int lane = threadIdx.x & 63;
    int n = ntile * 64 + lane;

    const float* xp = x + ((size_t)b * C_ + wu * 96) * N_ + n;
    const float* wp = ws + OFF_W2 + ((size_t)b * C_ + wu * 96) * 48;

    float acc[48];
#pragma unroll
    for (int m = 0; m < 48; ++m) acc[m] = 0.f;

#pragma unroll 2
    for (int cc = 0; cc < 96; ++cc) {
        float xv = xp[(size_t)cc * N_];
        const float4* wr4 = (const float4*)(wp + cc * 48);
#pragma unroll
        for (int j = 0; j < 12; ++j) {
            float4 w4 = wr4[j];
            acc[j * 4 + 0] = fmaf(xv, w4.x, acc[j * 4 + 0]);
            acc[j * 4 + 1] = fmaf(xv, w4.y, acc[j * 4 + 1]);
            acc[j * 4 + 2] = fmaf(xv, w4.z, acc[j * 4 + 2]);
            acc[j * 4 + 3] = fmaf(xv, w4.w, acc[j * 4 + 3]);
        }
    }

    __shared__ float red[4 * 48 * 64];
    int n_r = threadIdx.x & 63;
    int mb  = threadIdx.x >> 6;    // 0..7
    float fin[6];

    if (wv < 4) {
#pragma unroll
        for (int m = 0; m < 48; ++m) red[(wv * 48 + m) * 64 + lane] = acc[m];
    }
    __syncthreads();
#pragma unroll
    for (int k = 0; k < 6; ++k) {
        int m = k * 8 + mb;
        fin[k] = (red[(0 * 48 + m) * 64 + n_r] + red[(1 * 48 + m) * 64 + n_r])
               + (red[(2 * 48 + m) * 64 + n_r] + red[(3 * 48 + m) * 64 + n_r]);
    }
    __syncthreads();
    if (wv >= 4) {
#pragma unroll
        for (int m = 0; m < 48; ++m) red[((wv - 4) * 48 + m) * 64 + lane] = acc[m];
    }
    __syncthreads();
#pragma unroll
    for (int k = 0; k < 6; ++k) {
        int m = k * 8 + mb;
        fin[k] += (red[(0 * 48 + m) * 64 + n_r] + red[(1 * 48 + m) * 64 + n_r])
                + (red[(2 * 48 + m) * 64 + n_r] + red[(3 * 48 + m) * 64 + n_r]);
    }

    ushort_t* qB  = (ushort_t*)(ws + OFF_QB);
    ushort_t* kB  = (ushort_t*)(ws + OFF_KB);
    ushort_t* vBt = (ushort_t*)(ws + OFF_VB);
    int nn = ntile * 64 + n_r;
    size_t nb = (size_t)(b * N_ + nn) * RC_;
#pragma unroll
    for (int k = 0; k < 6; ++k) {
        int m = k * 8 + mb;
        float v = fin[k] + ws[OFF_B2 + b * 48 + m];
        if (m < 16)      qB[nb + m]        = f2bf(v);
        else if (m < 32) kB[nb + (m - 16)] = f2bf(v);
        else             vBt[((size_t)b * RC_ + (m - 32)) * N_ + nn] = f2bf(v);
    }
}

// ---------------------------------------------------------------- K3: MFMA flash attention
// Wave-uniform defer-max (THR=8), -m folded into MFMA C-in, l via ones-column.
__global__ __launch_bounds__(256) void k_attn(
        const ushort_t* __restrict__ qB, const ushort_t* __restrict__ kB,
        const ushort_t* __restrict__ vBt, const ushort_t* __restrict__ onesp,
        float* __restrict__ opart, float* __restrict__ mpart, float* __restrict__ lpart,
        int JS, int jrange) {
    int js = blockIdx.x % JS;
    int t  = blockIdx.x / JS;
    int itile = t & 31;
    int b = t >> 5;
    int wave = threadIdx.x >> 6;
    int lane = threadIdx.x & 63;
    int hi   = lane >> 5;
    int l31  = lane & 31;
    int i0 = itile * 128 + wave * 32;

    bf16x8 qf = *(const bf16x8*)&qB[((size_t)b * N_ + i0 + l31) * RC_ + hi * 8];

    f32x16 o, z;
#pragma unroll
    for (int r = 0; r < 16; ++r) { o[r] = 0.f; z[r] = 0.f; }
    float m = 0.f;   // wave-uniform running max (scores bounded; z = -m)

    int j0 = js * jrange;
    const ushort_t* kbase = kB + (size_t)b * N_ * RC_;
    const ushort_t* vbase = (l31 < 16) ? (vBt + ((size_t)b * RC_ + l31) * N_) : onesp;

    bf16x8 kf  = *(const bf16x8*)&kbase[(size_t)(j0 + l31) * RC_ + hi * 8];
    bf16x8 vf0 = *(const bf16x8*)&vbase[j0 + hi * 8];
    bf16x8 vf1 = *(const bf16x8*)&vbase[j0 + 16 + hi * 8];

    for (int jt = 0; jt < jrange; jt += 32) {
        int jn = j0 + jt + 32;
        bf16x8 kf2, vf02, vf12;
        if (jt + 32 < jrange) {
            kf2  = *(const bf16x8*)&kbase[(size_t)(jn + l31) * RC_ + hi * 8];
            vf02 = *(const bf16x8*)&vbase[jn + hi * 8];
            vf12 = *(const bf16x8*)&vbase[jn + 16 + hi * 8];
        }

        // d[r] = S[i=l31][j(jt,r,hi)] - m   (C-in = -m, log2 domain)
        f32x16 d = __builtin_amdgcn_mfma_f32_32x32x16_bf16(kf, qf, z, 0, 0, 0);

        // lane-local max of the 16 shifted scores (tree)
        float a0 = fmaxf(fmaxf(d[0], d[1]),  fmaxf(d[2], d[3]));
        float a1 = fmaxf(fmaxf(d[4], d[5]),  fmaxf(d[6], d[7]));
        float a2 = fmaxf(fmaxf(d[8], d[9]),  fmaxf(d[10], d[11]));
        float a3 = fmaxf(fmaxf(d[12], d[13]), fmaxf(d[14], d[15]));
        float tm = fmaxf(fmaxf(a0, a1), fmaxf(a2, a3));

        float p[16];
        if (__any(tm > 8.f)) {            // rare: raise m, rescale o (incl. l-col)
            float wm = tm;
#pragma unroll
            for (int off = 1; off < 64; off <<= 1)
                wm = fmaxf(wm, __shfl_xor(wm, off));
            float al = __builtin_amdgcn_exp2f(-wm);
            m += wm;
#pragma unroll
            for (int r = 0; r < 16; ++r) z[r] = -m;
#pragma unroll
            for (int r = 0; r < 16; ++r) o[r] *= al;
#pragma unroll
            for (int r = 0; r < 16; ++r) p[r] = __builtin_amdgcn_exp2f(d[r] - wm);
        } else {
#pragma unroll
            for (int r = 0; r < 16; ++r) p[r] = __builtin_amdgcn_exp2f(d[r]);
        }

        // pack p -> bf16 pairs (HW cvt_pk), exchange halves, assemble PV A-frags
        u32 W[8];
#pragma unroll
        for (int w = 0; w < 8; ++w) W[w] = cvt_pk_bf16(p[2 * w], p[2 * w + 1]);
        u32 PW[8];
#pragma unroll
        for (int w = 0; w < 8; ++w) PW[w] = (u32)__shfl_xor((int)W[w], 32);

        u32 fa[4], fb[4];
        fa[0] = hi ? PW[2] : W[0];  fa[1] = hi ? PW[3] : W[1];
        fa[2] = hi ? W[2] : PW[0];  fa[3] = hi ? W[3] : PW[1];
        fb[0] = hi ? PW[6] : W[4];  fb[1] = hi ? PW[7] : W[5];
        fb[2] = hi ? W[6] : PW[4];  fb[3] = hi ? W[7] : PW[5];

        o = __builtin_amdgcn_mfma_f32_32x32x16_bf16(*(bf16x8*)fa, vf0, o, 0, 0, 0);
        o = __builtin_amdgcn_mfma_f32_32x32x16_bf16(*(bf16x8*)fb, vf1, o, 0, 0, 0);

        kf = kf2; vf0 = vf02; vf1 = vf12;
    }

    // stores: o[r] is [i = 8*(r>>2)+4*hi+(r&3)] x [col = l31]; col<16 = rc, col16 = l
    if (l31 < 16) {
        size_t base = ((size_t)(b * JS + js) * RC_ + l31) * N_ + i0;
#pragma unroll
        for (int qd = 0; qd < 4; ++qd) {
            float4 st = {o[4 * qd + 0], o[4 * qd + 1], o[4 * qd + 2], o[4 * qd + 3]};
            *(float4*)&opart[base + 8 * qd + 4 * hi] = st;
        }
    }
    size_t mlbase = (size_t)(b * JS + js) * N_ + i0;
    if (l31 == 16) {
#pragma unroll
        for (int r = 0; r < 16; ++r)
            lpart[mlbase + 8 * (r >> 2) + 4 * hi + (r & 3)] = o[r];
    }
    if (hi == 0) mpart[mlbase + l31] = m;
}

// ---------------------------------------------------------------- K3b: merge j-split partials
__global__ __launch_bounds__(256) void k_amerge(
        const float* __restrict__ opart, const float* __restrict__ mpart,
        const float* __restrict__ lpart, float* __restrict__ aoT, int JS) {
    int gid = blockIdx.x * 256 + threadIdx.x;   // 131072
    int i  = gid & 4095;
    int t2 = gid >> 12;
    int b  = t2 >> 2;
    int rg = t2 & 3;

    float M = -1e30f;
    for (int js = 0; js < JS; ++js)
        M = fmaxf(M, mpart[(size_t)(b * JS + js) * N_ + i]);
    float w[16];
    float L = 0.f;
    for (int js = 0; js < JS; ++js) {
        float mv = mpart[(size_t)(b * JS + js) * N_ + i];
        float lv = lpart[(size_t)(b * JS + js) * N_ + i];
        w[js] = __builtin_amdgcn_exp2f(mv - M);
        L = fmaf(lv, w[js], L);
    }
    float inv = 1.f / L;
    float out[4] = {0.f, 0.f, 0.f, 0.f};
    for (int js = 0; js < JS; ++js) {
        size_t base = ((size_t)(b * JS + js) * RC_ + rg * 4) * N_ + i;
#pragma unroll
        for (int r = 0; r < 4; ++r)
            out[r] = fmaf(opart[base + (size_t)r * N_], w[js], out[r]);
    }
    float4 res = {out[0] * inv, out[1] * inv, out[2] * inv, out[3] * inv};
    *(float4*)&aoT[((size_t)(b * N_ + i) * RC_) + rg * 4] = res;
}

// ---------------------------------------------------------------- K4: proj (RC->C) + residual
__global__ __launch_bounds__(256) void k_proj(
        const float* __restrict__ x, const float* __restrict__ pw,
        const float* __restrict__ pb, const float* __restrict__ aoT,
        float* __restrict__ out) {
    int ch = blockIdx.x % 12;
    int t  = blockIdx.x / 12;
    int ntile = t & 15;
    int b = t >> 4;
    int n = ntile * 256 + threadIdx.x;

    const float4* a4 = (const float4*)&aoT[(size_t)(b * N_ + n) * RC_];
    float4 A0 = a4[0], A1 = a4[1], A2 = a4[2], A3 = a4[3];
    float av[16] = {A0.x, A0.y, A0.z, A0.w, A1.x, A1.y, A1.z, A1.w,
                    A2.x, A2.y, A2.z, A2.w, A3.x, A3.y, A3.z, A3.w};

    __shared__ float plds[64 * 16];
    __shared__ float pblds[64];
    int c0 = ch * 64;
    for (int idx = threadIdx.x; idx < 1024; idx += 256)
        plds[idx] = pw[(size_t)c0 * 16 + idx];
    if (threadIdx.x < 64) pblds[threadIdx.x] = pb[c0 + threadIdx.x];
    __syncthreads();

    for (int cc = 0; cc < 64; ++cc) {
        size_t xi = ((size_t)(b * 768 + c0 + cc)) * N_ + n;
        const float* wp = &plds[cc * 16];
        float t0 = fmaf(av[0],  wp[0],  pblds[cc] + x[xi]);
        float t1 = fmaf(av[1],  wp[1],  0.f);
        float t2 = fmaf(av[2],  wp[2],  0.f);
        float t3 = fmaf(av[3],  wp[3],  0.f);
#pragma unroll
        for (int r = 4; r < 16; r += 4) {
            t0 = fmaf(av[r + 0], wp[r + 0], t0);
            t1 = fmaf(av[r + 1], wp[r + 1], t1);
            t2 = fmaf(av[r + 2], wp[r + 2], t2);
            t3 = fmaf(av[r + 3], wp[r + 3], t3);
        }
        out[xi] = (t0 + t1) + (t2 + t3);
    }
}

// ---------------------------------------------------------------- launch
extern "C" void kernel_launch(void* const* d_in, const int* in_sizes, int n_in,
                              void* d_out, int out_size, void* d_ws, size_t ws_size,
                              hipStream_t stream) {
    const float* x    = (const float*)d_in[0];
    const float* gn_w = (const float*)d_in[1];
    const float* gn_b = (const float*)d_in[2];
    const float* qw   = (const float*)d_in[3];
    const float* qb   = (const float*)d_in[4];
    const float* kw   = (const float*)d_in[5];
    const float* kb   = (const float*)d_in[6];
    const float* vw   = (const float*)d_in[7];
    const float* vb   = (const float*)d_in[8];
    const float* pw   = (const float*)d_in[9];
    const float* pb   = (const float*)d_in[10];
    float* out = (float*)d_out;
    float* wsf = (float*)d_ws;

    size_t avail = ws_size / 4;   // floats
    int JS = 8;
    while (JS > 1) {
        size_t need = (size_t)OFF_PART + (size_t)JS * ((size_t)B_ * RC_ * N_ + 2 * (size_t)B_ * N_);
        if (need <= avail) break;
        JS >>= 1;
    }
    int jrange = N_ / JS;

    float* aoT = wsf + OFF_AO;
    const ushort_t* qB    = (const ushort_t*)(wsf + OFF_QB);
    const ushort_t* kB    = (const ushort_t*)(wsf + OFF_KB);
    const ushort_t* vBt   = (const ushort_t*)(wsf + OFF_VB);
    const ushort_t* onesp = (const ushort_t*)(wsf + OFF_ONES);
    float* opart = wsf + OFF_PART;
    float* mpart = opart + (size_t)B_ * JS * RC_ * N_;
    float* lpart = mpart + (size_t)B_ * JS * N_;

    k_init<<<8, 256, 0, stream>>>(wsf);
    k_stats<<<16 * 128, 256, 0, stream>>>(x, wsf);
    k_fold<<<24, 256, 0, stream>>>(gn_w, qw, kw, vw, wsf);
    k_bias<<<96, 256, 0, stream>>>(gn_w, gn_b, qw, qb, kw, kb, vw, vb, wsf);
    k_qkv<<<B_ * 64, 512, 0, stream>>>(x, wsf);
    k_attn<<<B_ * 32 * JS, 256, 0, stream>>>(qB, kB, vBt, onesp, opart, mpart, lpart, JS, jrange);
    k_amerge<<<512, 256, 0, stream>>>(opart, mpart, lpart, aoT, JS);
    k_proj<<<B_ * 16 * 12, 256, 0, stream>>>(x, pw, pb, aoT, out);
}